// Round 1
// baseline (2285.859 us; speedup 1.0000x reference)
//
#include <hip/hip_runtime.h>
#include <math.h>

#define N_ROWS 12288
#define DIM 256
#define K_TOP 32

// ---------------- Kernel 1: L2 row normalize ----------------
// One block per row; 256 threads == 256 dims.
__global__ __launch_bounds__(256) void normalize_rows(const float* __restrict__ x,
                                                      float* __restrict__ xn) {
    int row = blockIdx.x;
    int t = threadIdx.x;
    float v = x[(size_t)row * DIM + t];
    float sq = v * v;
    #pragma unroll
    for (int off = 32; off > 0; off >>= 1)
        sq += __shfl_down(sq, off, 64);
    __shared__ float ws[4];
    if ((t & 63) == 0) ws[t >> 6] = sq;
    __syncthreads();
    float total = ws[0] + ws[1] + ws[2] + ws[3];
    float norm = fmaxf(sqrtf(total), 1e-12f);
    xn[(size_t)row * DIM + t] = v / norm;
}

// ---------------- Kernel 2: adj = xn @ xn^T (fp32) ----------------
// 128x128 block tile, BK=16, 256 threads, 8x8 outputs/thread.
#define BM 128
#define BN 128
#define BK 16

__global__ __launch_bounds__(256) void gemm_nt(const float* __restrict__ A,
                                               float* __restrict__ C) {
    __shared__ float As[BK][BM];
    __shared__ float Bs[BK][BN];
    int bi = blockIdx.y, bj = blockIdx.x;
    int tid = threadIdx.x;
    int tx = tid & 15, ty = tid >> 4;
    float acc[8][8] = {};
    const float* Abase = A + (size_t)(bi * BM) * DIM;
    const float* Bbase = A + (size_t)(bj * BN) * DIM;

    for (int k0 = 0; k0 < DIM; k0 += BK) {
        #pragma unroll
        for (int l = 0; l < 2; ++l) {
            int idx = tid + l * 256;      // 0..511
            int r = idx >> 2;             // row in tile 0..127
            int q = idx & 3;              // float4 quad 0..3 (16 floats/row)
            float4 av = *(const float4*)(Abase + (size_t)r * DIM + k0 + q * 4);
            As[q * 4 + 0][r] = av.x; As[q * 4 + 1][r] = av.y;
            As[q * 4 + 2][r] = av.z; As[q * 4 + 3][r] = av.w;
            float4 bv = *(const float4*)(Bbase + (size_t)r * DIM + k0 + q * 4);
            Bs[q * 4 + 0][r] = bv.x; Bs[q * 4 + 1][r] = bv.y;
            Bs[q * 4 + 2][r] = bv.z; Bs[q * 4 + 3][r] = bv.w;
        }
        __syncthreads();
        #pragma unroll
        for (int kk = 0; kk < BK; ++kk) {
            float a[8], b[8];
            *(float4*)&a[0] = *(const float4*)&As[kk][ty * 8];
            *(float4*)&a[4] = *(const float4*)&As[kk][ty * 8 + 4];
            *(float4*)&b[0] = *(const float4*)&Bs[kk][tx * 8];
            *(float4*)&b[4] = *(const float4*)&Bs[kk][tx * 8 + 4];
            #pragma unroll
            for (int i = 0; i < 8; ++i)
                #pragma unroll
                for (int j = 0; j < 8; ++j)
                    acc[i][j] = fmaf(a[i], b[j], acc[i][j]);
        }
        __syncthreads();
    }
    #pragma unroll
    for (int i = 0; i < 8; ++i) {
        size_t row = (size_t)(bi * BM + ty * 8 + i);
        float* outp = C + row * N_ROWS + bj * BN + tx * 8;
        *(float4*)outp = *(float4*)&acc[i][0];
        *(float4*)(outp + 4) = *(float4*)&acc[i][4];
    }
}

// ---------------- Kernel 3: exact per-row top-K mask ----------------
// One block (256 threads) per row. Order-preserving u32 keys in LDS,
// 4-round radix select for the rank-32 key, ties broken by lowest index
// (matches jax.lax.top_k stability). In-place masked rewrite.
__device__ __forceinline__ unsigned int f2key(float f) {
    unsigned int u = __float_as_uint(f);
    return (u & 0x80000000u) ? ~u : (u | 0x80000000u);
}
__device__ __forceinline__ float key2f(unsigned int k) {
    unsigned int u = (k & 0x80000000u) ? (k ^ 0x80000000u) : ~k;
    return __uint_as_float(u);
}

__global__ __launch_bounds__(256) void topk_mask(float* __restrict__ adj) {
    __shared__ unsigned int keys[N_ROWS];   // 48 KB
    __shared__ unsigned int hist[256];
    __shared__ unsigned int tie_idx[256];
    __shared__ unsigned int bcast[4];
    __shared__ unsigned int s_tiecount;

    int row = blockIdx.x;
    int t = threadIdx.x;
    float* rp = adj + (size_t)row * N_ROWS;

    for (int j = t; j < N_ROWS; j += 256)
        keys[j] = f2key(rp[j]);

    unsigned int prefix = 0;
    int rank = K_TOP;       // 1-indexed rank from the top
    int gt_total = 0;       // keys strictly greater than v*
    for (int shift = 24; shift >= 0; shift -= 8) {
        hist[t] = 0;
        __syncthreads();
        unsigned int himask = (shift == 24) ? 0u : (0xFFFFFFFFu << (shift + 8));
        for (int j = t; j < N_ROWS; j += 256) {
            unsigned int key = keys[j];
            if ((key & himask) == prefix)
                atomicAdd(&hist[(key >> shift) & 0xFFu], 1u);
        }
        __syncthreads();
        if (t == 0) {
            int cum = 0, b = 255;
            for (; b >= 0; --b) {
                cum += (int)hist[b];
                if (cum >= rank) break;
            }
            bcast[0] = (unsigned)b;
            bcast[1] = (unsigned)(cum - (int)hist[b]);  // strictly above chosen bin
        }
        __syncthreads();
        unsigned int b = bcast[0];
        int above = (int)bcast[1];
        gt_total += above;
        rank -= above;
        prefix |= (b << shift);
    }
    unsigned int vstar = prefix;
    int need = K_TOP - gt_total;   // >= 1 by construction

    if (t == 0) s_tiecount = 0;
    __syncthreads();
    for (int j = t; j < N_ROWS; j += 256) {
        if (keys[j] == vstar) {
            unsigned int p = atomicAdd(&s_tiecount, 1u);
            if (p < 256u) tie_idx[p] = (unsigned)j;
        }
    }
    __syncthreads();
    if (t == 0) {
        int tiecount = (int)s_tiecount;
        if (tiecount > 256) tiecount = 256;
        // partial selection sort: put `need` smallest tie indices first
        int lim = (need < tiecount) ? need : tiecount;
        for (int a = 0; a < lim; ++a) {
            int mi = a;
            for (int b2 = a + 1; b2 < tiecount; ++b2)
                if (tie_idx[b2] < tie_idx[mi]) mi = b2;
            unsigned tmp = tie_idx[a]; tie_idx[a] = tie_idx[mi]; tie_idx[mi] = tmp;
        }
        bcast[2] = (tiecount >= need) ? tie_idx[need - 1] : 0xFFFFFFFFu;
    }
    __syncthreads();
    unsigned int cutoff = bcast[2];

    for (int j = t; j < N_ROWS; j += 256) {
        unsigned int key = keys[j];
        bool inc = (key > vstar) || (key == vstar && (unsigned)j <= cutoff);
        rp[j] = inc ? key2f(key) : 0.0f;
    }
}

extern "C" void kernel_launch(void* const* d_in, const int* in_sizes, int n_in,
                              void* d_out, int out_size, void* d_ws, size_t ws_size,
                              hipStream_t stream) {
    const float* x = (const float*)d_in[0];
    float* out = (float*)d_out;
    float* xn = (float*)d_ws;   // 12288*256*4 = 12.6 MB scratch

    normalize_rows<<<N_ROWS, 256, 0, stream>>>(x, xn);
    dim3 grid(N_ROWS / BN, N_ROWS / BM);
    gemm_nt<<<grid, 256, 0, stream>>>(xn, out);
    topk_mask<<<N_ROWS, 256, 0, stream>>>(out);
}

// Round 2
// 1934.173 us; speedup vs baseline: 1.1818x; 1.1818x over previous
//
#include <hip/hip_runtime.h>
#include <math.h>

#define N_ROWS 12288
#define DIM 256
#define K_TOP 32

// ---------------- Kernel 1: L2 row normalize ----------------
__global__ __launch_bounds__(256) void normalize_rows(const float* __restrict__ x,
                                                      float* __restrict__ xn) {
    int row = blockIdx.x;
    int t = threadIdx.x;
    float v = x[(size_t)row * DIM + t];
    float sq = v * v;
    #pragma unroll
    for (int off = 32; off > 0; off >>= 1)
        sq += __shfl_down(sq, off, 64);
    __shared__ float ws[4];
    if ((t & 63) == 0) ws[t >> 6] = sq;
    __syncthreads();
    float total = ws[0] + ws[1] + ws[2] + ws[3];
    float norm = fmaxf(sqrtf(total), 1e-12f);
    xn[(size_t)row * DIM + t] = v / norm;
}

// ---------------- Kernel 2: symmetric adj = xn @ xn^T (fp32) ----------------
// Only bi <= bj tiles computed; mirror tile written via LDS transpose.
// Double-buffered LDS staging, one barrier per K-iteration.
#define BM 128
#define BN 128
#define BK 16

__global__ __launch_bounds__(256) void gemm_sym(const float* __restrict__ A,
                                                float* __restrict__ C) {
    int bj = blockIdx.x, bi = blockIdx.y;
    if (bi > bj) return;
    __shared__ float As[2][BK][BM];   // 16 KB
    __shared__ float Bs[2][BK][BN];   // 16 KB
    __shared__ float Tr[32][132];     // 16.5 KB transpose staging
    int tid = threadIdx.x;
    int tx = tid & 15, ty = tid >> 4;
    int r0 = tid >> 2, q0 = tid & 3;  // staging: row 0..63 (+64), float4 quad 0..3
    const float* Abase = A + (size_t)(bi * BM) * DIM;
    const float* Bbase = A + (size_t)(bj * BN) * DIM;
    float acc[8][8] = {};
    float4 pa0, pa1, pb0, pb1;

    // prologue: load + stage k0 = 0
    pa0 = *(const float4*)(Abase + (size_t)r0 * DIM + q0 * 4);
    pa1 = *(const float4*)(Abase + (size_t)(r0 + 64) * DIM + q0 * 4);
    pb0 = *(const float4*)(Bbase + (size_t)r0 * DIM + q0 * 4);
    pb1 = *(const float4*)(Bbase + (size_t)(r0 + 64) * DIM + q0 * 4);
    {
        As[0][q0 * 4 + 0][r0] = pa0.x; As[0][q0 * 4 + 1][r0] = pa0.y;
        As[0][q0 * 4 + 2][r0] = pa0.z; As[0][q0 * 4 + 3][r0] = pa0.w;
        As[0][q0 * 4 + 0][r0 + 64] = pa1.x; As[0][q0 * 4 + 1][r0 + 64] = pa1.y;
        As[0][q0 * 4 + 2][r0 + 64] = pa1.z; As[0][q0 * 4 + 3][r0 + 64] = pa1.w;
        Bs[0][q0 * 4 + 0][r0] = pb0.x; Bs[0][q0 * 4 + 1][r0] = pb0.y;
        Bs[0][q0 * 4 + 2][r0] = pb0.z; Bs[0][q0 * 4 + 3][r0] = pb0.w;
        Bs[0][q0 * 4 + 0][r0 + 64] = pb1.x; Bs[0][q0 * 4 + 1][r0 + 64] = pb1.y;
        Bs[0][q0 * 4 + 2][r0 + 64] = pb1.z; Bs[0][q0 * 4 + 3][r0 + 64] = pb1.w;
    }
    __syncthreads();

    int p = 0;
    #pragma unroll 1
    for (int it = 0; it < DIM / BK; ++it) {
        bool has_next = (it + 1) < (DIM / BK);
        if (has_next) {
            int k0 = (it + 1) * BK;
            pa0 = *(const float4*)(Abase + (size_t)r0 * DIM + k0 + q0 * 4);
            pa1 = *(const float4*)(Abase + (size_t)(r0 + 64) * DIM + k0 + q0 * 4);
            pb0 = *(const float4*)(Bbase + (size_t)r0 * DIM + k0 + q0 * 4);
            pb1 = *(const float4*)(Bbase + (size_t)(r0 + 64) * DIM + k0 + q0 * 4);
        }
        #pragma unroll
        for (int kk = 0; kk < BK; ++kk) {
            float a[8], b[8];
            *(float4*)&a[0] = *(const float4*)&As[p][kk][ty * 8];
            *(float4*)&a[4] = *(const float4*)&As[p][kk][ty * 8 + 4];
            *(float4*)&b[0] = *(const float4*)&Bs[p][kk][tx * 8];
            *(float4*)&b[4] = *(const float4*)&Bs[p][kk][tx * 8 + 4];
            #pragma unroll
            for (int i = 0; i < 8; ++i)
                #pragma unroll
                for (int j = 0; j < 8; ++j)
                    acc[i][j] = fmaf(a[i], b[j], acc[i][j]);
        }
        if (has_next) {
            int np = p ^ 1;
            As[np][q0 * 4 + 0][r0] = pa0.x; As[np][q0 * 4 + 1][r0] = pa0.y;
            As[np][q0 * 4 + 2][r0] = pa0.z; As[np][q0 * 4 + 3][r0] = pa0.w;
            As[np][q0 * 4 + 0][r0 + 64] = pa1.x; As[np][q0 * 4 + 1][r0 + 64] = pa1.y;
            As[np][q0 * 4 + 2][r0 + 64] = pa1.z; As[np][q0 * 4 + 3][r0 + 64] = pa1.w;
            Bs[np][q0 * 4 + 0][r0] = pb0.x; Bs[np][q0 * 4 + 1][r0] = pb0.y;
            Bs[np][q0 * 4 + 2][r0] = pb0.z; Bs[np][q0 * 4 + 3][r0] = pb0.w;
            Bs[np][q0 * 4 + 0][r0 + 64] = pb1.x; Bs[np][q0 * 4 + 1][r0 + 64] = pb1.y;
            Bs[np][q0 * 4 + 2][r0 + 64] = pb1.z; Bs[np][q0 * 4 + 3][r0 + 64] = pb1.w;
        }
        __syncthreads();
        p ^= 1;
    }

    // direct tile write (rows bi*BM.., cols bj*BN..)
    #pragma unroll
    for (int i = 0; i < 8; ++i) {
        float* outp = C + (size_t)(bi * BM + ty * 8 + i) * N_ROWS + bj * BN + tx * 8;
        *(float4*)outp = *(float4*)&acc[i][0];
        *(float4*)(outp + 4) = *(float4*)&acc[i][4];
    }
    if (bi == bj) return;

    // mirror tile write via LDS transpose, 32-column chunks
    #pragma unroll 1
    for (int c = 0; c < 4; ++c) {
        __syncthreads();
        if ((tx >> 2) == c) {
            int tcl = tx & 3;
            #pragma unroll
            for (int j = 0; j < 8; ++j)
                #pragma unroll
                for (int i = 0; i < 8; ++i)
                    Tr[tcl * 8 + j][ty * 8 + i] = acc[i][j];
        }
        __syncthreads();
        int rr = tid >> 3;            // 0..31
        int cc = (tid & 7) * 16;      // 0..112
        float* dst = C + (size_t)(bj * BN + c * 32 + rr) * N_ROWS + bi * BM + cc;
        *(float4*)(dst + 0)  = *(const float4*)&Tr[rr][cc + 0];
        *(float4*)(dst + 4)  = *(const float4*)&Tr[rr][cc + 4];
        *(float4*)(dst + 8)  = *(const float4*)&Tr[rr][cc + 8];
        *(float4*)(dst + 12) = *(const float4*)&Tr[rr][cc + 12];
    }
}

// ---------------- Kernel 3: exact per-row top-K mask, register-resident ----------------
__device__ __forceinline__ unsigned int f2key(float f) {
    unsigned int u = __float_as_uint(f);
    return (u & 0x80000000u) ? ~u : (u | 0x80000000u);
}
__device__ __forceinline__ unsigned long long shfl_down_u64(unsigned long long x, int off) {
    unsigned int lo = (unsigned int)x, hi = (unsigned int)(x >> 32);
    lo = __shfl_down(lo, off, 64);
    hi = __shfl_down(hi, off, 64);
    return ((unsigned long long)hi << 32) | lo;
}
__device__ __forceinline__ unsigned long long composite(float v, int j) {
    return ((unsigned long long)f2key(v) << 32) | (unsigned int)(N_ROWS - j);
}

#define CAND_CAP 2048

__global__ __launch_bounds__(256) void topk_mask(float* __restrict__ adj) {
    __shared__ float cval[CAND_CAP];
    __shared__ int cidx[CAND_CAP];
    __shared__ int count;
    __shared__ unsigned long long red[4];

    int row = blockIdx.x;
    int t = threadIdx.x;
    float* rp = adj + (size_t)row * N_ROWS;

    // one coalesced read of the whole row into registers: 12 x float4 / thread
    float4 v[12];
    #pragma unroll
    for (int c = 0; c < 12; ++c)
        v[c] = ((const float4*)rp)[c * 256 + t];
    // element (c, comp) has column j = 4*(c*256+t)+comp

    // candidate compaction with adaptive threshold (exact: candidates ⊇ top-K when count ≥ K)
    float T = 0.145f;
    int M;
    #pragma unroll 1
    while (true) {
        if (t == 0) count = 0;
        __syncthreads();
        #pragma unroll
        for (int c = 0; c < 12; ++c) {
            int jb = 4 * (c * 256 + t);
            float4 w = v[c];
            if (w.x > T) { int p = atomicAdd(&count, 1); if (p < CAND_CAP) { cval[p] = w.x; cidx[p] = jb + 0; } }
            if (w.y > T) { int p = atomicAdd(&count, 1); if (p < CAND_CAP) { cval[p] = w.y; cidx[p] = jb + 1; } }
            if (w.z > T) { int p = atomicAdd(&count, 1); if (p < CAND_CAP) { cval[p] = w.z; cidx[p] = jb + 2; } }
            if (w.w > T) { int p = atomicAdd(&count, 1); if (p < CAND_CAP) { cval[p] = w.w; cidx[p] = jb + 3; } }
        }
        __syncthreads();
        M = count < CAND_CAP ? count : CAND_CAP;
        if (M >= K_TOP) break;       // uniform condition
        T -= 0.04f;
        __syncthreads();             // protect count reset next iteration
    }

    // select rank-K composite by K rounds of block argmax over M candidates
    unsigned long long cutoff = 0;
    #pragma unroll 1
    for (int r2 = 0; r2 < K_TOP; ++r2) {
        unsigned long long best = 0;
        for (int p2 = t; p2 < M; p2 += 256) {
            int id = cidx[p2];
            if (id >= 0) {
                unsigned long long comp = composite(cval[p2], id);
                if (comp > best) best = comp;
            }
        }
        #pragma unroll
        for (int off = 32; off > 0; off >>= 1) {
            unsigned long long o = shfl_down_u64(best, off);
            if (o > best) best = o;
        }
        if ((t & 63) == 0) red[t >> 6] = best;
        __syncthreads();
        unsigned long long win = red[0];
        if (red[1] > win) win = red[1];
        if (red[2] > win) win = red[2];
        if (red[3] > win) win = red[3];
        cutoff = win;
        int jwin = N_ROWS - (int)(win & 0xFFFFFFFFu);
        __syncthreads();
        for (int p2 = t; p2 < M; p2 += 256)
            if (cidx[p2] == jwin) cidx[p2] = -1;
        __syncthreads();
    }

    // masked write from registers (one coalesced pass)
    #pragma unroll
    for (int c = 0; c < 12; ++c) {
        int jb = 4 * (c * 256 + t);
        float4 w = v[c];
        float4 o;
        o.x = (composite(w.x, jb + 0) >= cutoff) ? w.x : 0.0f;
        o.y = (composite(w.y, jb + 1) >= cutoff) ? w.y : 0.0f;
        o.z = (composite(w.z, jb + 2) >= cutoff) ? w.z : 0.0f;
        o.w = (composite(w.w, jb + 3) >= cutoff) ? w.w : 0.0f;
        ((float4*)rp)[c * 256 + t] = o;
    }
}

extern "C" void kernel_launch(void* const* d_in, const int* in_sizes, int n_in,
                              void* d_out, int out_size, void* d_ws, size_t ws_size,
                              hipStream_t stream) {
    const float* x = (const float*)d_in[0];
    float* out = (float*)d_out;
    float* xn = (float*)d_ws;   // 12.6 MB scratch

    normalize_rows<<<N_ROWS, 256, 0, stream>>>(x, xn);
    dim3 grid(N_ROWS / BN, N_ROWS / BM);
    gemm_sym<<<grid, 256, 0, stream>>>(xn, out);
    topk_mask<<<N_ROWS, 256, 0, stream>>>(out);
}